// Round 2
// baseline (1785.013 us; speedup 1.0000x reference)
//
#include <hip/hip_runtime.h>
#include <hip/hip_fp16.h>

#define B_ 2
#define S_ 2048
#define D_ 2048
#define H_ 16
#define DH_ 128
#define FF_ 8192

typedef _Float16 f16x8 __attribute__((ext_vector_type(8)));
typedef float f32x4 __attribute__((ext_vector_type(4)));

// global_load_lds: per-lane global src, wave-uniform LDS base (+lane*16 implicit)
#define GLD16(gsrc, ldst) __builtin_amdgcn_global_load_lds( \
    (__attribute__((address_space(1))) void*)(uintptr_t)(gsrc), \
    (__attribute__((address_space(3))) void*)(ldst), 16, 0, 0)

// ---------------- RoPE table (mimics numpy f32 pipeline) ----------------
// numpy: inv_freq f32, ang = pos * inv_freq in f32, then sin/cos.
__global__ void build_rope_tab(float* __restrict__ tab) {
  const int pos = blockIdx.x;       // 0..2047
  const int i = threadIdx.x;        // 0..63 pair index
  float ex = (float)(2 * i) / 128.0f;
  float invf = (float)(1.0 / pow(10000.0, (double)ex));  // f32-rounded
  float ang = (float)pos * invf;                          // f32 mult (as numpy)
  tab[(size_t)pos * 128 + 2 * i]     = (float)sin((double)ang);
  tab[(size_t)pos * 128 + 2 * i + 1] = (float)cos((double)ang);
}

// ---------------- transpose + cast f32[R][C] -> f16[C][R] ----------------
__global__ void tcast(const float* __restrict__ in, _Float16* __restrict__ out,
                      int R, int C) {
  __shared__ float tile[32][33];
  const int c0 = blockIdx.x * 32, r0 = blockIdx.y * 32;
  const int tx = threadIdx.x, ty = threadIdx.y;  // (32,8)
#pragma unroll
  for (int i = 0; i < 32; i += 8)
    tile[ty + i][tx] = in[(size_t)(r0 + ty + i) * C + c0 + tx];
  __syncthreads();
#pragma unroll
  for (int i = 0; i < 32; i += 8)
    out[(size_t)(c0 + ty + i) * R + r0 + tx] = (_Float16)tile[tx][ty + i];
}

// ---------------- LayerNorm (optional residual add, f16 + optional f32 out) ----
__global__ __launch_bounds__(256) void ln_fused(
    const float* __restrict__ x, const float* __restrict__ add,
    const float* __restrict__ g, const float* __restrict__ bv,
    _Float16* __restrict__ outh, float* __restrict__ outf) {
  const int row = blockIdx.x, tid = threadIdx.x;
  const size_t base = (size_t)row * D_;
  const float4* xp = (const float4*)(x + base) + tid * 2;
  float4 a0 = xp[0], a1 = xp[1];
  if (add) {
    const float4* ap = (const float4*)(add + base) + tid * 2;
    float4 b0 = ap[0], b1 = ap[1];
    a0.x += b0.x; a0.y += b0.y; a0.z += b0.z; a0.w += b0.w;
    a1.x += b1.x; a1.y += b1.y; a1.z += b1.z; a1.w += b1.w;
  }
  float v[8] = {a0.x, a0.y, a0.z, a0.w, a1.x, a1.y, a1.z, a1.w};
  float s1 = 0.f, s2 = 0.f;
#pragma unroll
  for (int j = 0; j < 8; ++j) { s1 += v[j]; s2 += v[j] * v[j]; }
#pragma unroll
  for (int off = 32; off; off >>= 1) {
    s1 += __shfl_xor(s1, off);
    s2 += __shfl_xor(s2, off);
  }
  __shared__ float red[8];
  __shared__ float mv[2];
  if ((tid & 63) == 0) { red[tid >> 6] = s1; red[4 + (tid >> 6)] = s2; }
  __syncthreads();
  if (tid == 0) {
    float t1 = red[0] + red[1] + red[2] + red[3];
    float t2 = red[4] + red[5] + red[6] + red[7];
    float mean = t1 * (1.0f / D_);
    float var = t2 * (1.0f / D_) - mean * mean;
    mv[0] = mean; mv[1] = rsqrtf(var + 1e-5f);
  }
  __syncthreads();
  const float mean = mv[0], rstd = mv[1];
  const int c0 = tid * 8;
#pragma unroll
  for (int j = 0; j < 8; ++j) {
    float nv = (v[j] - mean) * rstd * g[c0 + j] + bv[c0 + j];
    outh[base + c0 + j] = (_Float16)nv;
    if (outf) outf[base + c0 + j] = nv;
  }
}

// ---------------- GEMM: A[M][K] f16 x Bt[N][K] f16 -> out[M][N] --------------
// 128x128 tile, BK=32, 4 waves (each 64x64), global_load_lds width-16 staging.
// MODE 0: f16 out. 1: f32 out. 2: f16 gelu(acc+bias). 3: f32 acc+bias+res.
template <int MODE>
__global__ __launch_bounds__(256) void gemm_bt(
    const _Float16* __restrict__ A, const _Float16* __restrict__ Bt,
    float* __restrict__ outF, _Float16* __restrict__ outH,
    const float* __restrict__ bias, const float* __restrict__ res,
    int M, int N, int K) {
  __shared__ _Float16 lsA[128 * 32];
  __shared__ _Float16 lsB[128 * 32];
  const int tid = threadIdx.x;
  const int w = tid >> 6, l = tid & 63;
  const int l4 = l >> 4, l15 = l & 15;
  const int m0 = blockIdx.y * 128, n0 = blockIdx.x * 128;
  const int wm = (w >> 1) * 64, wn = (w & 1) * 64;
  const int srow = l >> 2, schunk = (l & 3) * 8;
  f32x4 acc[4][4] = {};
  for (int k0 = 0; k0 < K; k0 += 32) {
#pragma unroll
    for (int i = 0; i < 2; ++i) {
      const int ai = w * 2 + i;
      const _Float16* ga = A + (size_t)(m0 + ai * 16 + srow) * K + k0 + schunk;
      GLD16(ga, lsA + ai * 512);
      const _Float16* gb = Bt + (size_t)(n0 + ai * 16 + srow) * K + k0 + schunk;
      GLD16(gb, lsB + ai * 512);
    }
    __syncthreads();
    f16x8 af[4], bf[4];
#pragma unroll
    for (int mi = 0; mi < 4; ++mi)
      af[mi] = *(const f16x8*)(lsA + (wm + mi * 16 + l15) * 32 + l4 * 8);
#pragma unroll
    for (int ni = 0; ni < 4; ++ni)
      bf[ni] = *(const f16x8*)(lsB + (wn + ni * 16 + l15) * 32 + l4 * 8);
#pragma unroll
    for (int mi = 0; mi < 4; ++mi)
#pragma unroll
      for (int ni = 0; ni < 4; ++ni)
        acc[mi][ni] = __builtin_amdgcn_mfma_f32_16x16x32_f16(
            af[mi], bf[ni], acc[mi][ni], 0, 0, 0);
    __syncthreads();
  }
#pragma unroll
  for (int mi = 0; mi < 4; ++mi) {
#pragma unroll
    for (int r = 0; r < 4; ++r) {
      const int row = m0 + wm + mi * 16 + l4 * 4 + r;
#pragma unroll
      for (int ni = 0; ni < 4; ++ni) {
        const int col = n0 + wn + ni * 16 + l15;
        float v = acc[mi][ni][r];
        if (MODE == 0) {
          outH[(size_t)row * N + col] = (_Float16)v;
        } else if (MODE == 1) {
          outF[(size_t)row * N + col] = v;
        } else if (MODE == 2) {
          v += bias[col];
          v = 0.5f * v * (1.0f + erff(v * 0.70710678118654752f));
          outH[(size_t)row * N + col] = (_Float16)v;
        } else {
          v += bias[col] + res[(size_t)row * N + col];
          outF[(size_t)row * N + col] = v;
        }
      }
    }
  }
}

// ---------------- RoPE on q,k: qkv[4096][6144] f16 -> qr,kr [32][2048][128] ---
// Each lane: one quarter-head (32 elems = 16 rotary pairs) for q and k.
__global__ __launch_bounds__(256) void rope_qk(
    const _Float16* __restrict__ qkv, const int* __restrict__ pos_ids,
    const float* __restrict__ tab, _Float16* __restrict__ qr,
    _Float16* __restrict__ kr) {
  const int tid = threadIdx.x, w = tid >> 6, l = tid & 63;
  const int idx = blockIdx.x * 4 + w;  // b*S + s
  const int b = idx >> 11, s = idx & 2047;
  const int pos = pos_ids[idx];
  const int h = l >> 2, qtr = l & 3;   // head 0..15, quarter 0..3
  const float* tp = tab + (size_t)pos * 128 + qtr * 32;  // 16 (sin,cos) pairs
  float sn[16], cs[16];
#pragma unroll
  for (int j = 0; j < 16; ++j) { sn[j] = tp[2 * j]; cs[j] = tp[2 * j + 1]; }
#pragma unroll
  for (int sec = 0; sec < 2; ++sec) {
    const _Float16* src = qkv + (size_t)idx * 6144 + sec * 2048 + h * 128 + qtr * 32;
    int4 dv[4];
    const int4* sp = (const int4*)src;
#pragma unroll
    for (int c = 0; c < 4; ++c) dv[c] = sp[c];
    const _Float16* e = (const _Float16*)dv;
    int4 ov[4];
    _Float16* o = (_Float16*)ov;
#pragma unroll
    for (int j = 0; j < 16; ++j) {
      float x0 = (float)e[2 * j], x1 = (float)e[2 * j + 1];
      o[2 * j]     = (_Float16)(x0 * cs[j] - x1 * sn[j]);
      o[2 * j + 1] = (_Float16)(x1 * cs[j] + x0 * sn[j]);
    }
    _Float16* dst = (sec ? kr : qr) + ((size_t)(b * H_ + h) * S_ + s) * DH_ + qtr * 32;
    int4* dp = (int4*)dst;
#pragma unroll
    for (int c = 0; c < 4; ++c) dp[c] = ov[c];
  }
}

// ---------------- V transpose: qkv v-section -> vt[32][128][2048] ------------
__global__ void vtrans(const _Float16* __restrict__ qkv, _Float16* __restrict__ vt) {
  __shared__ _Float16 tile[32][33];
  const int bh = blockIdx.z;
  const int b = bh >> 4, h = bh & 15;
  const int s0 = blockIdx.x * 32, d0 = blockIdx.y * 32;
  const int tx = threadIdx.x, ty = threadIdx.y;  // (32,8)
  const _Float16* src = qkv + (size_t)(b * S_) * 6144 + 4096 + h * 128;
#pragma unroll
  for (int i = 0; i < 32; i += 8)
    tile[ty + i][tx] = src[(size_t)(s0 + ty + i) * 6144 + d0 + tx];
  __syncthreads();
  _Float16* dst = vt + (size_t)bh * DH_ * S_;
#pragma unroll
  for (int i = 0; i < 32; i += 8)
    dst[(size_t)(d0 + ty + i) * S_ + s0 + tx] = tile[tx][ty + i];
}

// ---------------- flash attention pass A: O, m, l ---------------------------
__global__ __launch_bounds__(256) void attn_flash(
    const _Float16* __restrict__ qr, const _Float16* __restrict__ kr,
    const _Float16* __restrict__ vt, _Float16* __restrict__ attnO,
    float* __restrict__ mOut, float* __restrict__ lOut) {
  __shared__ _Float16 kt_lds[64 * 136];   // [64 keys][128 dh] pad+8
  __shared__ _Float16 vt_lds[128 * 72];   // [128 dh][64 keys] pad+8
  __shared__ _Float16 p_lds[4 * 16 * 72]; // per-wave [16 q][64 k] pad+8
  const int tid = threadIdx.x, w = tid >> 6, l = tid & 63;
  const int l4 = l >> 4, l15 = l & 15;
  const int qt = blockIdx.x, h = blockIdx.y, b = blockIdx.z;
  const int bh = b * H_ + h;
  const int q0 = qt * 64;
  const int qrowA = q0 + w * 16 + l15;  // A-frag row
  f16x8 aq[4];
  const _Float16* qbase = qr + ((size_t)bh * S_ + qrowA) * DH_;
#pragma unroll
  for (int ks = 0; ks < 4; ++ks)
    aq[ks] = *(const f16x8*)(qbase + ks * 32 + l4 * 8);
  float m_r[4], l_r[4];
  f32x4 accO[8] = {};
#pragma unroll
  for (int r = 0; r < 4; ++r) { m_r[r] = -1e30f; l_r[r] = 0.f; }
  const int krow = tid >> 2, kc4 = tid & 3;
  const int vdh = tid >> 1, vc = tid & 1;
  _Float16* pw = p_lds + w * 16 * 72;
  for (int kt = 0; kt <= qt; ++kt) {
    const int kbase = kt * 64;
    {  // stage K tile + V tile (padded, reg-staged)
      const _Float16* src = kr + ((size_t)bh * S_ + kbase + krow) * DH_ + kc4 * 32;
      _Float16* dst = kt_lds + krow * 136 + kc4 * 32;
#pragma unroll
      for (int jj = 0; jj < 4; ++jj)
        *(int4*)(dst + jj * 8) = *(const int4*)(src + jj * 8);
      const _Float16* vsrc = vt + ((size_t)bh * DH_ + vdh) * S_ + kbase + vc * 32;
      _Float16* vdst = vt_lds + vdh * 72 + vc * 32;
#pragma unroll
      for (int jj = 0; jj < 4; ++jj)
        *(int4*)(vdst + jj * 8) = *(const int4*)(vsrc + jj * 8);
    }
    __syncthreads();
    f32x4 sc[4] = {};
#pragma unroll
    for (int ni = 0; ni < 4; ++ni)
#pragma unroll
      for (int ks = 0; ks < 4; ++ks) {
        f16x8 bk = *(const f16x8*)(kt_lds + (ni * 16 + l15) * 136 + ks * 32 + l4 * 8);
        sc[ni] = __builtin_amdgcn_mfma_f32_16x16x32_f16(aq[ks], bk, sc[ni], 0, 0, 0);
      }
    if (kt == qt) {  // causal mask on diagonal tile
#pragma unroll
      for (int ni = 0; ni < 4; ++ni)
#pragma unroll
        for (int r = 0; r < 4; ++r) {
          const int col = kbase + ni * 16 + l15;
          const int rowq = q0 + w * 16 + l4 * 4 + r;
          if (col > rowq) sc[ni][r] = -1e30f;
        }
    }
    float scale_r[4];
#pragma unroll
    for (int r = 0; r < 4; ++r) {
      float tmax = fmaxf(fmaxf(sc[0][r], sc[1][r]), fmaxf(sc[2][r], sc[3][r]));
#pragma unroll
      for (int off = 1; off < 16; off <<= 1)
        tmax = fmaxf(tmax, __shfl_xor(tmax, off));
      const float mnew = fmaxf(m_r[r], tmax);
      const float scl = __expf(m_r[r] - mnew);
      float ps = 0.f;
#pragma unroll
      for (int ni = 0; ni < 4; ++ni) {
        float pv = __expf(sc[ni][r] - mnew);
        sc[ni][r] = pv;
        ps += pv;
      }
#pragma unroll
      for (int off = 1; off < 16; off <<= 1) ps += __shfl_xor(ps, off);
      l_r[r] = l_r[r] * scl + ps;
      m_r[r] = mnew;
      scale_r[r] = scl;
    }
#pragma unroll
    for (int oi = 0; oi < 8; ++oi)
#pragma unroll
      for (int r = 0; r < 4; ++r) accO[oi][r] *= scale_r[r];
    // P: D-layout -> LDS -> A-layout
#pragma unroll
    for (int ni = 0; ni < 4; ++ni)
#pragma unroll
      for (int r = 0; r < 4; ++r)
        pw[(l4 * 4 + r) * 72 + ni * 16 + l15] = (_Float16)sc[ni][r];
#pragma unroll
    for (int ks2 = 0; ks2 < 2; ++ks2) {
      f16x8 pa = *(const f16x8*)(pw + l15 * 72 + ks2 * 32 + l4 * 8);
#pragma unroll
      for (int oi = 0; oi < 8; ++oi) {
        f16x8 bv = *(const f16x8*)(vt_lds + (oi * 16 + l15) * 72 + ks2 * 32 + l4 * 8);
        accO[oi] = __builtin_amdgcn_mfma_f32_16x16x32_f16(pa, bv, accO[oi], 0, 0, 0);
      }
    }
    __syncthreads();
  }
#pragma unroll
  for (int r = 0; r < 4; ++r) {
    const float inv = 1.0f / l_r[r];
    const int rowq = q0 + w * 16 + l4 * 4 + r;
#pragma unroll
    for (int oi = 0; oi < 8; ++oi) {
      attnO[((size_t)(b * S_ + rowq) * H_ + h) * DH_ + oi * 16 + l15] =
          (_Float16)(accO[oi][r] * inv);
    }
    if (l15 == 0) {
      mOut[(size_t)bh * S_ + rowq] = m_r[r];
      lOut[(size_t)bh * S_ + rowq] = l_r[r];
    }
  }
}

// ---------------- pass B: recompute scores, write P f32 to d_out ------------
__global__ __launch_bounds__(256) void attn_pwrite(
    const _Float16* __restrict__ qr, const _Float16* __restrict__ kr,
    const float* __restrict__ mIn, const float* __restrict__ lIn,
    float* __restrict__ outP) {
  __shared__ _Float16 kt_lds[64 * 136];
  const int tid = threadIdx.x, w = tid >> 6, l = tid & 63;
  const int l4 = l >> 4, l15 = l & 15;
  const int kt = blockIdx.x, qt = blockIdx.y, bh = blockIdx.z;
  const int q0 = qt * 64, kbase = kt * 64;
  float* tileout = outP + ((size_t)bh * S_ + q0) * S_ + kbase;
  if (kt > qt) {  // fully-masked tile: zeros
    const int r = tid >> 2, cc = (tid & 3) * 16;
    float4 z = {0.f, 0.f, 0.f, 0.f};
    float4* dst = (float4*)(tileout + (size_t)r * S_ + cc);
#pragma unroll
    for (int i = 0; i < 4; ++i) dst[i] = z;
    return;
  }
  {
    const int krow = tid >> 2, kc4 = tid & 3;
    const _Float16* src = kr + ((size_t)bh * S_ + kbase + krow) * DH_ + kc4 * 32;
    _Float16* dst = kt_lds + krow * 136 + kc4 * 32;
#pragma unroll
    for (int jj = 0; jj < 4; ++jj)
      *(int4*)(dst + jj * 8) = *(const int4*)(src + jj * 8);
  }
  const int qrowA = q0 + w * 16 + l15;
  f16x8 aq[4];
  const _Float16* qbase = qr + ((size_t)bh * S_ + qrowA) * DH_;
#pragma unroll
  for (int ks = 0; ks < 4; ++ks)
    aq[ks] = *(const f16x8*)(qbase + ks * 32 + l4 * 8);
  __syncthreads();
  f32x4 sc[4] = {};
#pragma unroll
  for (int ni = 0; ni < 4; ++ni)
#pragma unroll
    for (int ks = 0; ks < 4; ++ks) {
      f16x8 bk = *(const f16x8*)(kt_lds + (ni * 16 + l15) * 136 + ks * 32 + l4 * 8);
      sc[ni] = __builtin_amdgcn_mfma_f32_16x16x32_f16(aq[ks], bk, sc[ni], 0, 0, 0);
    }
  const bool diag = (kt == qt);
#pragma unroll
  for (int r = 0; r < 4; ++r) {
    const int rowq = q0 + w * 16 + l4 * 4 + r;
    const float mv = mIn[(size_t)bh * S_ + rowq];
    const float linv = 1.0f / lIn[(size_t)bh * S_ + rowq];
#pragma unroll
    for (int ni = 0; ni < 4; ++ni) {
      const int col = kbase + ni * 16 + l15;
      float pv = __expf(sc[ni][r] - mv) * linv;
      if (diag && col > rowq) pv = 0.f;
      tileout[(size_t)(w * 16 + l4 * 4 + r) * S_ + ni * 16 + l15] = pv;
    }
  }
}

// ---------------- launch --------------------------------------------------
extern "C" void kernel_launch(void* const* d_in, const int* in_sizes, int n_in,
                              void* d_out, int out_size, void* d_ws, size_t ws_size,
                              hipStream_t stream) {
  (void)in_sizes; (void)n_in; (void)out_size; (void)ws_size;
  const float* hidden   = (const float*)d_in[0];
  const int*   pos_ids  = (const int*)d_in[1];
  const float* wq       = (const float*)d_in[2];
  const float* wk       = (const float*)d_in[3];
  const float* wv       = (const float*)d_in[4];
  const float* wo       = (const float*)d_in[5];
  const float* ln1_g    = (const float*)d_in[6];
  const float* ln1_b    = (const float*)d_in[7];
  const float* ln2_g    = (const float*)d_in[8];
  const float* ln2_b    = (const float*)d_in[9];
  const float* fc_in_w  = (const float*)d_in[10];
  const float* fc_in_b  = (const float*)d_in[11];
  const float* fc_out_w = (const float*)d_in[12];
  const float* fc_out_b = (const float*)d_in[13];

  float* out1 = (float*)d_out;                       // [B,S,D] f32
  float* outP = out1 + (size_t)B_ * S_ * D_;         // [B,H,S,S] f32

  char* ws = (char*)d_ws;
  size_t off = 0;
  auto alloc = [&](size_t bytes) {
    char* p = ws + off;
    off += (bytes + 255) & ~(size_t)255;
    return p;
  };
  _Float16* h1h     = (_Float16*)alloc((size_t)4096 * 2048 * 2);   // 16.8M
  _Float16* qkvT    = (_Float16*)alloc((size_t)6144 * 2048 * 2);   // 25.2M
  _Float16* woT     = (_Float16*)alloc((size_t)2048 * 2048 * 2);   // 8.4M
  _Float16* fc_inT  = (_Float16*)alloc((size_t)8192 * 2048 * 2);   // 33.6M
  _Float16* fc_outT = (_Float16*)alloc((size_t)2048 * 8192 * 2);   // 33.6M
  _Float16* qkv     = (_Float16*)alloc((size_t)4096 * 6144 * 2);   // 50.3M
  _Float16* qrB     = (_Float16*)alloc((size_t)32 * 2048 * 128 * 2); // 16.8M
  _Float16* krB     = (_Float16*)alloc((size_t)32 * 2048 * 128 * 2); // 16.8M
  _Float16* vtB     = (_Float16*)alloc((size_t)32 * 128 * 2048 * 2); // 16.8M
  _Float16* attnO   = (_Float16*)alloc((size_t)4096 * 2048 * 2);   // 16.8M
  float* mbuf = (float*)alloc((size_t)32 * 2048 * 4);
  float* lbuf = (float*)alloc((size_t)32 * 2048 * 4);
  float* rtab = (float*)alloc((size_t)2048 * 128 * 4);             // 1M
  // aliases (lifetimes disjoint):
  float*     attn_out = (float*)h1h;      // 33.5M over h1h+qkvT (dead post-GEMM1)
  _Float16*  ffn1     = qkv;              // 67.1M over qkv+qr (dead post-passB)
  float*     h2f      = (float*)krB;      // 33.5M over kr+vt (dead post-passB)
  _Float16*  h2h      = attnO;            // 16.8M (dead post-GEMM2)

  const dim3 tb(32, 8);
  build_rope_tab<<<2048, 64, 0, stream>>>(rtab);
  tcast<<<dim3(64, 64), tb, 0, stream>>>(wq, qkvT, 2048, 2048);
  tcast<<<dim3(64, 64), tb, 0, stream>>>(wk, qkvT + (size_t)2048 * 2048, 2048, 2048);
  tcast<<<dim3(64, 64), tb, 0, stream>>>(wv, qkvT + (size_t)4096 * 2048, 2048, 2048);
  tcast<<<dim3(64, 64), tb, 0, stream>>>(wo, woT, 2048, 2048);
  tcast<<<dim3(256, 64), tb, 0, stream>>>(fc_in_w, fc_inT, 2048, 8192);
  tcast<<<dim3(64, 256), tb, 0, stream>>>(fc_out_w, fc_outT, 8192, 2048);
  ln_fused<<<4096, 256, 0, stream>>>(hidden, nullptr, ln1_g, ln1_b, h1h, nullptr);
  gemm_bt<0><<<dim3(48, 32), 256, 0, stream>>>(h1h, qkvT, nullptr, qkv,
                                               nullptr, nullptr, 4096, 6144, 2048);
  rope_qk<<<1024, 256, 0, stream>>>(qkv, pos_ids, rtab, qrB, krB);
  vtrans<<<dim3(64, 4, 32), tb, 0, stream>>>(qkv, vtB);
  attn_flash<<<dim3(32, 16, 2), 256, 0, stream>>>(qrB, krB, vtB, attnO, mbuf, lbuf);
  attn_pwrite<<<dim3(32, 32, 32), 256, 0, stream>>>(qrB, krB, mbuf, lbuf, outP);
  gemm_bt<1><<<dim3(16, 32), 256, 0, stream>>>(attnO, woT, attn_out, nullptr,
                                               nullptr, nullptr, 4096, 2048, 2048);
  ln_fused<<<4096, 256, 0, stream>>>(hidden, attn_out, ln2_g, ln2_b, h2h, h2f);
  gemm_bt<2><<<dim3(64, 32), 256, 0, stream>>>(h2h, fc_inT, nullptr, ffn1,
                                               fc_in_b, nullptr, 4096, 8192, 2048);
  gemm_bt<3><<<dim3(16, 32), 256, 0, stream>>>(ffn1, fc_outT, out1, nullptr,
                                               fc_out_b, h2f, 4096, 2048, 8192);
}